// Round 2
// baseline (660.371 us; speedup 1.0000x reference)
//
#include <hip/hip_runtime.h>
#include <hip/hip_bf16.h>

// CrissCrossAttentionBlock: B=8, H=W=96, C=512, c=64. N = 73728 pixels.
// External tensors fp32. Internals: xb,q,k,vth,vtv,yv,Av,Ah bf16; S fp32.
//
// Pipeline:
//  0) conv_x: x fp32 -> xb bf16 (row-major); conv_w x3: W fp32 -> fragment-major bf16
//  1) mfma_proj x2: q,k (Nx64 bf16) via 16x16x32 bf16 MFMA
//  1b) proj_v_th: V projection, w-major pixels, writes vth[c][b*9216+h*96+w] (w-contig)
//  1c) proj_v_tv: V projection, h-major pixels, writes vtv[c][b*9216+w*96+h] (h-contig)
//      -> both aggregations get K-contiguous B-fragments straight from global.
//  2) cc_scores (MFMA, no LDS): S[n][0:96] vertical (diag -1e30), [96:192] horizontal
//  3) cc_softmax: per-pixel softmax over 192 logits; writes bf16 probs Av/Ah
//     INTO the S rows (Av at short 0..95, Ah at short 96..191 of each 768B row)
//  4) cc_aggr_v (MFMA, LDS-free): yv = Av @ V, B-frags streamed from vtv
//  5) cc_aggr_h_final (MFMA, LDS-free): out = (yv + Ah@V)*gamma + x, B-frags from vth

#define NPIX 73728
#define HH 96
#define WW 96
#define CC 512
#define CQ 64
#define PA 384   // short-pitch of A rows embedded in S rows (768 B)

typedef __attribute__((ext_vector_type(8))) short bf16x8;
typedef __attribute__((ext_vector_type(4))) float f32x4;

__device__ __forceinline__ void async16(const void* g, void* l) {
    __builtin_amdgcn_global_load_lds(
        (const __attribute__((address_space(1))) unsigned int*)g,
        (__attribute__((address_space(3))) unsigned int*)l,
        16, 0, 0);
}

__device__ __forceinline__ short bf16s(float f) {
    __hip_bfloat16 h = __float2bfloat16(f);
    return *reinterpret_cast<short*>(&h);
}

// ---------------------------------------------------------------------------
// 0a) x fp32 -> bf16, row-major. 8 elems per thread.
// ---------------------------------------------------------------------------
__global__ __launch_bounds__(256) void conv_x(
    const float* __restrict__ x, short* __restrict__ xb)
{
    size_t i8 = ((size_t)blockIdx.x * 256 + threadIdx.x) * 8;
    float4 a = *reinterpret_cast<const float4*>(x + i8);
    float4 b = *reinterpret_cast<const float4*>(x + i8 + 4);
    union { __hip_bfloat16 h[8]; uint4 u; } pk;
    pk.h[0] = __float2bfloat16(a.x); pk.h[1] = __float2bfloat16(a.y);
    pk.h[2] = __float2bfloat16(a.z); pk.h[3] = __float2bfloat16(a.w);
    pk.h[4] = __float2bfloat16(b.x); pk.h[5] = __float2bfloat16(b.y);
    pk.h[6] = __float2bfloat16(b.z); pk.h[7] = __float2bfloat16(b.w);
    *reinterpret_cast<uint4*>(xb + i8) = pk.u;
}

// ---------------------------------------------------------------------------
// 0b) W (512 x J fp32, row-major) -> B-fragment-major bf16:
//     dst[((kb32*(J/16)+ntile)*64 + lane)*8 + j] =
//        W[kb32*32 + (lane>>4)*8 + j][ntile*16 + (lane&15)]
// ---------------------------------------------------------------------------
__global__ __launch_bounds__(256) void conv_w(
    const float* __restrict__ W, short* __restrict__ dst, int J)
{
    int idx = blockIdx.x * 256 + threadIdx.x;   // one 8-elem fragment per thread
    int lane = idx & 63;
    int blk = idx >> 6;
    int ntiles = J >> 4;
    int ntile = blk % ntiles;
    int kb32 = blk / ntiles;
    int krow = kb32 * 32 + (lane >> 4) * 8;
    int col = ntile * 16 + (lane & 15);
    union { __hip_bfloat16 h[8]; uint4 u; } pk;
    #pragma unroll
    for (int j = 0; j < 8; ++j)
        pk.h[j] = __float2bfloat16(W[(size_t)(krow + j) * J + col]);
    *reinterpret_cast<uint4*>(dst + (size_t)idx * 8) = pk.u;
}

// ---------------------------------------------------------------------------
// 1) MFMA projection GEMM (q, k): out[n][j] = xb[n][:] @ W[:][j] + bias[j]
//    Row-major bf16 output. BN=64: 4 waves 4x1, each 32x64.
// ---------------------------------------------------------------------------
template <int BN>
__global__ __launch_bounds__(256) void mfma_proj(
    const short* __restrict__ Xb,    // N x 512 bf16
    const short* __restrict__ Wf,    // fragment-major bf16
    const float* __restrict__ bias,  // J fp32
    short* __restrict__ out,         // N x J bf16
    int J)
{
    __shared__ __align__(16) short Albuf[128 * 32];   // fragment-major, 8 KB
    const int tid = threadIdx.x;
    const int lane = tid & 63;
    const int w = tid >> 6;
    const int mBase = blockIdx.x * 128;
    const int nBase = blockIdx.y * BN;

    constexpr int MT = (BN == 128) ? 4 : 2;
    constexpr int NT = 4;
    const int wr = (BN == 128) ? (w >> 1) : w;
    const int wc = (BN == 128) ? (w & 1) : 0;
    const int tbase = wr * MT;
    const int nTile0 = (nBase >> 4) + wc * 4;
    const int ntilesJ = J >> 4;

    f32x4 acc[MT][NT];
    #pragma unroll
    for (int i = 0; i < MT; ++i)
        #pragma unroll
        for (int j = 0; j < NT; ++j) {
            f32x4 z = {0.f, 0.f, 0.f, 0.f};
            acc[i][j] = z;
        }

    const int arow0 = lane & 15;        // m within tile
    const int acol0 = (lane >> 4) * 8;  // k within 32

    for (int kb = 0; kb < 16; ++kb) {
        #pragma unroll
        for (int s = 0; s < 2; ++s) {
            int t = w * 2 + s;
            const short* g = Xb + (size_t)(mBase + t * 16 + arow0) * 512 + kb * 32 + acol0;
            async16(g, &Albuf[t * 512]);
        }
        __syncthreads();

        bf16x8 bf[NT];
        #pragma unroll
        for (int jn = 0; jn < NT; ++jn)
            bf[jn] = *reinterpret_cast<const bf16x8*>(
                Wf + ((size_t)(kb * ntilesJ + nTile0 + jn) * 64 + lane) * 8);
        bf16x8 af[MT];
        #pragma unroll
        for (int i = 0; i < MT; ++i)
            af[i] = *reinterpret_cast<const bf16x8*>(&Albuf[(tbase + i) * 512 + lane * 8]);
        #pragma unroll
        for (int i = 0; i < MT; ++i)
            #pragma unroll
            for (int jn = 0; jn < NT; ++jn)
                acc[i][jn] = __builtin_amdgcn_mfma_f32_16x16x32_bf16(
                    af[i], bf[jn], acc[i][jn], 0, 0, 0);
        __syncthreads();
    }

    // Epilogue: D[row=(lane>>4)*4+r][col=lane&15] per 16x16 tile.
    const int lrow = (lane >> 4) * 4, lcol = lane & 15;
    #pragma unroll
    for (int jn = 0; jn < NT; ++jn) {
        int col = nBase + wc * 64 + jn * 16 + lcol;
        float bc = bias[col];
        #pragma unroll
        for (int i = 0; i < MT; ++i) {
            int row = mBase + wr * (MT * 16) + i * 16 + lrow;
            #pragma unroll
            for (int r = 0; r < 4; ++r) {
                out[(size_t)(row + r) * J + col] = bf16s(acc[i][jn][r] + bc);
            }
        }
    }
}

// ---------------------------------------------------------------------------
// 1b) V projection, w-major pixels, writes vth[c][n] (n = b*9216+h*96+w).
//     1-D grid, slab-fastest: bid = mTile*4 + slab -> consecutive blocks share
//     the A-tile via L2. Tile 128 x 128, 4 waves 2x2 (64x64 each).
//     Epilogue packs 4 consecutive rows -> one 8B store per (i,jn).
// ---------------------------------------------------------------------------
__global__ __launch_bounds__(256) void proj_v_th(
    const short* __restrict__ Xb,
    const short* __restrict__ Wf,    // 512x512 fragment-major
    const float* __restrict__ bias,
    short* __restrict__ vth)         // [512][NPIX]
{
    __shared__ __align__(16) short Albuf[128 * 32];
    const int tid = threadIdx.x;
    const int lane = tid & 63;
    const int w = tid >> 6;
    const int bid = blockIdx.x;
    const int mBase = (bid >> 2) * 128;
    const int nBase = (bid & 3) * 128;

    const int wr = w >> 1, wc = w & 1;
    const int nTile0 = (nBase >> 4) + wc * 4;

    f32x4 acc[4][4];
    #pragma unroll
    for (int i = 0; i < 4; ++i)
        #pragma unroll
        for (int j = 0; j < 4; ++j) {
            f32x4 z = {0.f, 0.f, 0.f, 0.f};
            acc[i][j] = z;
        }

    const int arow0 = lane & 15;
    const int acol0 = (lane >> 4) * 8;

    for (int kb = 0; kb < 16; ++kb) {
        #pragma unroll
        for (int s = 0; s < 2; ++s) {
            int t = w * 2 + s;
            const short* g = Xb + (size_t)(mBase + t * 16 + arow0) * 512 + kb * 32 + acol0;
            async16(g, &Albuf[t * 512]);
        }
        __syncthreads();

        bf16x8 bf[4];
        #pragma unroll
        for (int jn = 0; jn < 4; ++jn)
            bf[jn] = *reinterpret_cast<const bf16x8*>(
                Wf + ((size_t)(kb * 32 + nTile0 + jn) * 64 + lane) * 8);
        bf16x8 af[4];
        #pragma unroll
        for (int i = 0; i < 4; ++i)
            af[i] = *reinterpret_cast<const bf16x8*>(&Albuf[(wr * 4 + i) * 512 + lane * 8]);
        #pragma unroll
        for (int i = 0; i < 4; ++i)
            #pragma unroll
            for (int jn = 0; jn < 4; ++jn)
                acc[i][jn] = __builtin_amdgcn_mfma_f32_16x16x32_bf16(
                    af[i], bf[jn], acc[i][jn], 0, 0, 0);
        __syncthreads();
    }

    const int lrow = (lane >> 4) * 4, lcol = lane & 15;
    #pragma unroll
    for (int jn = 0; jn < 4; ++jn) {
        int col = nBase + wc * 64 + jn * 16 + lcol;
        float bc = bias[col];
        #pragma unroll
        for (int i = 0; i < 4; ++i) {
            int row = mBase + wr * 64 + i * 16 + lrow;
            short4 st;
            st.x = bf16s(acc[i][jn][0] + bc);
            st.y = bf16s(acc[i][jn][1] + bc);
            st.z = bf16s(acc[i][jn][2] + bc);
            st.w = bf16s(acc[i][jn][3] + bc);
            *reinterpret_cast<short4*>(vth + (size_t)col * NPIX + row) = st;
        }
    }
}

// ---------------------------------------------------------------------------
// 1c) V projection, h-major pixels, writes vtv[c][b*9216+w*96+h] (h-contig).
//     Block = (b,w) pair x 128-c slab, slab-fastest. Tile 96 x 128:
//     4 waves 2x2, wave tile 48x64 (MT=3, NT=4). A-tile rows walk h
//     (pixel stride 96); global_load_lds takes per-lane global addresses.
// ---------------------------------------------------------------------------
__global__ __launch_bounds__(256) void proj_v_tv(
    const short* __restrict__ Xb,
    const short* __restrict__ Wf,    // 512x512 fragment-major
    const float* __restrict__ bias,
    short* __restrict__ vtv)         // [512][NPIX], h-contig pixel order
{
    __shared__ __align__(16) short Albuf[96 * 32];   // 6 KB
    const int tid = threadIdx.x;
    const int lane = tid & 63;
    const int wv = tid >> 6;
    const int bid = blockIdx.x;
    const int pair = bid >> 2;           // b*96 + w
    const int nBase = (bid & 3) * 128;
    const int b = pair / 96;
    const int w = pair - b * 96;
    const size_t colPix = (size_t)b * 9216 + w;   // pixel(h) = colPix + h*96
    const size_t wBase = (size_t)b * 9216 + (size_t)w * 96;  // vtv row base

    const int wr = wv >> 1, wc = wv & 1;
    const int nTile0 = (nBase >> 4) + wc * 4;

    f32x4 acc[3][4];
    #pragma unroll
    for (int i = 0; i < 3; ++i)
        #pragma unroll
        for (int j = 0; j < 4; ++j) {
            f32x4 z = {0.f, 0.f, 0.f, 0.f};
            acc[i][j] = z;
        }

    const int arow0 = lane & 15;
    const int acol0 = (lane >> 4) * 8;

    for (int kb = 0; kb < 16; ++kb) {
        #pragma unroll
        for (int s = 0; s < 2; ++s) {
            int t = s * 4 + wv;                       // wave-uniform
            if (t < 6) {
                const short* g = Xb + (colPix + (size_t)(t * 16 + arow0) * 96) * 512
                                    + kb * 32 + acol0;
                async16(g, &Albuf[t * 512]);
            }
        }
        __syncthreads();

        bf16x8 bf[4];
        #pragma unroll
        for (int jn = 0; jn < 4; ++jn)
            bf[jn] = *reinterpret_cast<const bf16x8*>(
                Wf + ((size_t)(kb * 32 + nTile0 + jn) * 64 + lane) * 8);
        bf16x8 af[3];
        #pragma unroll
        for (int i = 0; i < 3; ++i)
            af[i] = *reinterpret_cast<const bf16x8*>(&Albuf[(wr * 3 + i) * 512 + lane * 8]);
        #pragma unroll
        for (int i = 0; i < 3; ++i)
            #pragma unroll
            for (int jn = 0; jn < 4; ++jn)
                acc[i][jn] = __builtin_amdgcn_mfma_f32_16x16x32_bf16(
                    af[i], bf[jn], acc[i][jn], 0, 0, 0);
        __syncthreads();
    }

    const int lrow = (lane >> 4) * 4, lcol = lane & 15;
    #pragma unroll
    for (int jn = 0; jn < 4; ++jn) {
        int col = nBase + wc * 64 + jn * 16 + lcol;
        float bc = bias[col];
        #pragma unroll
        for (int i = 0; i < 3; ++i) {
            int h = wr * 48 + i * 16 + lrow;
            short4 st;
            st.x = bf16s(acc[i][jn][0] + bc);
            st.y = bf16s(acc[i][jn][1] + bc);
            st.z = bf16s(acc[i][jn][2] + bc);
            st.w = bf16s(acc[i][jn][3] + bc);
            *reinterpret_cast<short4*>(vtv + (size_t)col * NPIX + wBase + h) = st;
        }
    }
}

// ---------------------------------------------------------------------------
// 2) Scores via MFMA, no LDS. blockIdx.y==0: vertical, ==1: horizontal.
// ---------------------------------------------------------------------------
__global__ __launch_bounds__(256) void cc_scores(
    const short* __restrict__ Q,   // N x 64 bf16
    const short* __restrict__ K,   // N x 64 bf16
    float* __restrict__ S)         // N x 192 fp32
{
    const int tid = threadIdx.x;
    const int lane = tid & 63;
    const int wv = tid >> 6;
    const int wr = wv >> 1, wc = wv & 1;
    const bool vert = (blockIdx.y == 0);
    const int b = blockIdx.x / 96;
    const int line = blockIdx.x % 96;

    size_t base;
    int rowStride;
    if (vert) { base = (size_t)b * 9216 + line;       rowStride = 96; }
    else      { base = ((size_t)b * 96 + line) * 96;  rowStride = 1;  }

    const int cl = lane & 15;
    const int q8 = (lane >> 4) * 8;

    f32x4 acc[3][3];
    #pragma unroll
    for (int i = 0; i < 3; ++i)
        #pragma unroll
        for (int j = 0; j < 3; ++j) {
            f32x4 z = {0.f, 0.f, 0.f, 0.f};
            acc[i][j] = z;
        }

    #pragma unroll
    for (int kb = 0; kb < 2; ++kb) {
        bf16x8 af[3], bf[3];
        #pragma unroll
        for (int mt = 0; mt < 3; ++mt) {
            size_t n = base + (size_t)(wr * 48 + mt * 16 + cl) * rowStride;
            af[mt] = *reinterpret_cast<const bf16x8*>(Q + n * 64 + kb * 32 + q8);
        }
        #pragma unroll
        for (int nt = 0; nt < 3; ++nt) {
            size_t n = base + (size_t)(wc * 48 + nt * 16 + cl) * rowStride;
            bf[nt] = *reinterpret_cast<const bf16x8*>(K + n * 64 + kb * 32 + q8);
        }
        #pragma unroll
        for (int mt = 0; mt < 3; ++mt)
            #pragma unroll
            for (int nt = 0; nt < 3; ++nt)
                acc[mt][nt] = __builtin_amdgcn_mfma_f32_16x16x32_bf16(
                    af[mt], bf[nt], acc[mt][nt], 0, 0, 0);
    }

    const int lrow = (lane >> 4) * 4;
    const int dirOff = vert ? 0 : 96;
    #pragma unroll
    for (int mt = 0; mt < 3; ++mt) {
        #pragma unroll
        for (int r = 0; r < 4; ++r) {
            int i = wr * 48 + mt * 16 + lrow + r;
            size_t n = base + (size_t)i * rowStride;
            float* srow = S + n * 192 + dirOff;
            #pragma unroll
            for (int nt = 0; nt < 3; ++nt) {
                int j = wc * 48 + nt * 16 + cl;
                srow[j] = (vert && i == j) ? -1e30f : acc[mt][nt][r];
            }
        }
    }
}

// ---------------------------------------------------------------------------
// 3) Softmax over 192 logits per pixel. One wave per pixel.
//    Writes bf16 probabilities INTO the row: Av = shorts [0,96), Ah = [96,192).
// ---------------------------------------------------------------------------
__global__ __launch_bounds__(256) void cc_softmax(float* __restrict__ S)
{
    const int tid = threadIdx.x;
    const int lane = tid & 63;
    const size_t n = (size_t)blockIdx.x * 4 + (tid >> 6);
    float* row = S + n * 192;
    float s0 = row[lane], s1 = row[lane + 64], s2 = row[lane + 128];
    float m = fmaxf(s0, fmaxf(s1, s2));
    #pragma unroll
    for (int off = 32; off >= 1; off >>= 1) m = fmaxf(m, __shfl_xor(m, off, 64));
    float e0 = expf(s0 - m), e1 = expf(s1 - m), e2 = expf(s2 - m);
    float sum = e0 + e1 + e2;
    #pragma unroll
    for (int off = 32; off >= 1; off >>= 1) sum += __shfl_xor(sum, off, 64);
    float inv = 1.0f / sum;
    short p0 = bf16s(e0 * inv);
    short p1 = bf16s(e1 * inv);
    short p2 = bf16s(e2 * inv);
    short* av = reinterpret_cast<short*>(row);   // 96 shorts (cols 0..95  = Av)
    short* ah = av + 96;                         // 96 shorts (cols 96..191 = Ah)
    av[lane] = p0;
    if (lane < 32) av[64 + lane] = p1;
    else           ah[lane - 32] = p1;
    ah[32 + lane] = p2;
}

// ---------------------------------------------------------------------------
// 4) Vertical aggregation, LDS-free MFMA stream:
//    Yv[b,h,w][c] = sum_g Av[b,h,w][g] * V[b,g,w][c].  M=96(h) N=128(c) K=96(g).
//    B-frags 16B-contiguous from vtv. Block = (b,w) x slab, slab-fastest.
// ---------------------------------------------------------------------------
__global__ __launch_bounds__(256) void cc_aggr_v(
    const short* __restrict__ A,     // (short*)S: Av at n*PA
    const short* __restrict__ vtv,   // [512][b*9216+w*96+h]
    short* __restrict__ Yv)          // N x 512 bf16 (row-major pixels)
{
    const int tid = threadIdx.x;
    const int lane = tid & 63;
    const int wv = tid >> 6;
    const int bid = blockIdx.x;
    const int pair = bid >> 2;           // b*96 + w
    const int cBase = (bid & 3) * 128;
    const int b = pair / 96;
    const int w = pair - b * 96;
    const size_t pixBase = (size_t)b * 9216 + w;      // + h*96
    const size_t wBase = (size_t)b * 9216 + (size_t)w * 96;  // vtv: + g

    const int wr = wv >> 1, wc = wv & 1;     // wave tile 48(h) x 64(c)
    const int cl = lane & 15, q = lane >> 4;

    f32x4 acc[3][4];
    #pragma unroll
    for (int i = 0; i < 3; ++i)
        #pragma unroll
        for (int j = 0; j < 4; ++j) {
            f32x4 z = {0.f, 0.f, 0.f, 0.f};
            acc[i][j] = z;
        }

    #pragma unroll
    for (int kb = 0; kb < 3; ++kb) {
        bf16x8 af[3];
        #pragma unroll
        for (int mt = 0; mt < 3; ++mt) {
            size_t n = pixBase + (size_t)(wr * 48 + mt * 16 + cl) * 96;
            af[mt] = *reinterpret_cast<const bf16x8*>(A + n * PA + kb * 32 + q * 8);
        }
        #pragma unroll
        for (int nt = 0; nt < 4; ++nt) {
            int col = cBase + wc * 64 + nt * 16 + cl;
            bf16x8 bv = *reinterpret_cast<const bf16x8*>(
                vtv + (size_t)col * NPIX + wBase + kb * 32 + q * 8);
            #pragma unroll
            for (int mt = 0; mt < 3; ++mt)
                acc[mt][nt] = __builtin_amdgcn_mfma_f32_16x16x32_bf16(
                    af[mt], bv, acc[mt][nt], 0, 0, 0);
        }
    }

    const int lrow = q * 4;
    #pragma unroll
    for (int mt = 0; mt < 3; ++mt) {
        #pragma unroll
        for (int r = 0; r < 4; ++r) {
            size_t n = pixBase + (size_t)(wr * 48 + mt * 16 + lrow + r) * 96;
            #pragma unroll
            for (int nt = 0; nt < 4; ++nt) {
                int c = cBase + wc * 64 + nt * 16 + cl;
                Yv[n * 512 + c] = bf16s(acc[mt][nt][r]);
            }
        }
    }
}

// ---------------------------------------------------------------------------
// 5) Horizontal aggregation + epilogue, LDS-free MFMA stream:
//    out[n][c] = (Yv[n][c] + sum_u Ah[n][u] * V[rowBase+u][c]) * gamma + X[n][c]
// ---------------------------------------------------------------------------
__global__ __launch_bounds__(256) void cc_aggr_h_final(
    const short* __restrict__ A,             // (short*)S: Ah at n*PA + 96
    const short* __restrict__ vth,           // [512][pixel] (w-contig)
    const __hip_bfloat16* __restrict__ Yv,   // N x 512 bf16
    const float* __restrict__ X,             // N x 512 fp32
    const float* __restrict__ gamma_p,
    float* __restrict__ out)                 // N x 512 fp32
{
    const int tid = threadIdx.x;
    const int lane = tid & 63;
    const int wv = tid >> 6;
    const int bid = blockIdx.x;
    const int pair = bid >> 2;           // b*96 + h
    const int cBase = (bid & 3) * 128;
    const size_t rowBase = (size_t)pair * 96;   // pixel n = rowBase + u

    const int wr = wv >> 1, wc = wv & 1;     // wave tile 48(w) x 64(c)
    const int cl = lane & 15, q = lane >> 4;

    f32x4 acc[3][4];
    #pragma unroll
    for (int i = 0; i < 3; ++i)
        #pragma unroll
        for (int j = 0; j < 4; ++j) {
            f32x4 z = {0.f, 0.f, 0.f, 0.f};
            acc[i][j] = z;
        }

    #pragma unroll
    for (int kb = 0; kb < 3; ++kb) {
        bf16x8 af[3];
        #pragma unroll
        for (int mt = 0; mt < 3; ++mt) {
            size_t n = rowBase + (size_t)(wr * 48 + mt * 16 + cl);
            af[mt] = *reinterpret_cast<const bf16x8*>(A + n * PA + 96 + kb * 32 + q * 8);
        }
        #pragma unroll
        for (int nt = 0; nt < 4; ++nt) {
            int col = cBase + wc * 64 + nt * 16 + cl;
            bf16x8 bv = *reinterpret_cast<const bf16x8*>(
                vth + (size_t)col * NPIX + rowBase + kb * 32 + q * 8);
            #pragma unroll
            for (int mt = 0; mt < 3; ++mt)
                acc[mt][nt] = __builtin_amdgcn_mfma_f32_16x16x32_bf16(
                    af[mt], bv, acc[mt][nt], 0, 0, 0);
        }
    }

    const float gm = gamma_p[0];
    const int lrow = q * 4;
    #pragma unroll
    for (int mt = 0; mt < 3; ++mt) {
        #pragma unroll
        for (int r = 0; r < 4; ++r) {
            size_t rowOff = (rowBase + (size_t)(wr * 48 + mt * 16 + lrow + r)) * 512;
            #pragma unroll
            for (int nt = 0; nt < 4; ++nt) {
                size_t off = rowOff + cBase + wc * 64 + nt * 16 + cl;
                out[off] = (acc[mt][nt][r] + __bfloat162float(Yv[off])) * gm + X[off];
            }
        }
    }
}

// ---------------------------------------------------------------------------
extern "C" void kernel_launch(void* const* d_in, const int* in_sizes, int n_in,
                              void* d_out, int out_size, void* d_ws, size_t ws_size,
                              hipStream_t stream) {
    const float* x     = (const float*)d_in[0];
    const float* Wq    = (const float*)d_in[1];
    const float* bq    = (const float*)d_in[2];
    const float* Wk    = (const float*)d_in[3];
    const float* bk    = (const float*)d_in[4];
    const float* Wv    = (const float*)d_in[5];
    const float* bv    = (const float*)d_in[6];
    const float* gamma = (const float*)d_in[7];
    float* out = (float*)d_out;

    // Workspace (shorts unless noted); Yv aliases xb (dead after projections).
    //   xb  : NPIX*512        = 37,748,736
    //   Wqf : 512*64, Wkf : 512*64, Wvf : 512*512
    //   q,k : NPIX*64 each
    //   vth : NPIX*512  (c-major, w-contig pixels)
    //   vtv : NPIX*512  (c-major, h-contig pixels)
    //   S   : NPIX*192 fp32  (also hosts bf16 Av/Ah)     total ~303 MiB
    short* xb  = (short*)d_ws;
    short* Wqf = xb + (size_t)NPIX * 512;
    short* Wkf = Wqf + 512 * 64;
    short* Wvf = Wkf + 512 * 64;
    short* q   = Wvf + 512 * 512;
    short* k   = q + (size_t)NPIX * CQ;
    short* vth = k + (size_t)NPIX * CQ;
    short* vtv = vth + (size_t)NPIX * CC;
    float* S   = (float*)(vtv + (size_t)NPIX * CC);
    short* yv  = xb;   // alias: xb dead after the two V projection passes

    conv_x<<<NPIX * 512 / 8 / 256, 256, 0, stream>>>(x, xb);
    conv_w<<<16, 256, 0, stream>>>(Wq, Wqf, 64);
    conv_w<<<16, 256, 0, stream>>>(Wk, Wkf, 64);
    conv_w<<<128, 256, 0, stream>>>(Wv, Wvf, 512);

    mfma_proj<64><<<dim3(NPIX / 128, 1), 256, 0, stream>>>(xb, Wqf, bq, q, CQ);
    mfma_proj<64><<<dim3(NPIX / 128, 1), 256, 0, stream>>>(xb, Wkf, bk, k, CQ);
    proj_v_th<<<(NPIX / 128) * 4, 256, 0, stream>>>(xb, Wvf, bv, vth);
    proj_v_tv<<<768 * 4, 256, 0, stream>>>(xb, Wvf, bv, vtv);

    cc_scores<<<dim3(8 * 96, 2), 256, 0, stream>>>(q, k, S);
    cc_softmax<<<NPIX / 4, 256, 0, stream>>>(S);

    cc_aggr_v<<<768 * 4, 256, 0, stream>>>((const short*)S, vtv, yv);
    cc_aggr_h_final<<<768 * 4, 256, 0, stream>>>(
        (const short*)S, vth, (const __hip_bfloat16*)yv, x, gamma, out);
}

// Round 3
// 582.064 us; speedup vs baseline: 1.1345x; 1.1345x over previous
//
#include <hip/hip_runtime.h>
#include <hip/hip_bf16.h>

// CrissCrossAttentionBlock: B=8, H=W=96, C=512, c=64. N = 73728 pixels.
// External tensors fp32. Internals: q,k,vth,vtv,Yv,Av,Ah bf16; S fp32.
//
// Pipeline (9 launches):
//  0) conv_w x3: W fp32 -> fragment-major bf16
//  1) proj_qk: q,k (Nx64 bf16) from x fp32 (reg-staged bf16 A), fused, LDS-vectorized out
//  2) proj_v:  vth[c][b,h,w] (c-major) from x fp32, short4 column stores
//  3) transpose_vtv: vth -> vtv[c][b,w,h] via per-(c,b)-plane 96x96 LDS transpose
//  4) cc_scores (MFMA): S[n][0:96] vertical (diag -1e30), [96:192] horizontal,
//     LDS-staged float4 writes
//  5) cc_softmax: per-pixel softmax over 192 logits; writes bf16 probs Av/Ah in place
//  6) cc_aggr_v (MFMA, LDS-free loop): Yv = Av @ V from vtv; LDS-staged short8 stores
//  7) cc_aggr_h_final (MFMA): out = (Yv + Ah@V)*gamma + x; fp32 LDS stage, float4 I/O

#define NPIX 73728
#define CC 512
#define CQ 64
#define PA 384   // short-pitch of A rows embedded in S rows (768 B)

typedef __attribute__((ext_vector_type(8))) short bf16x8;
typedef __attribute__((ext_vector_type(4))) float f32x4;

__device__ __forceinline__ short bf16s(float f) {
    __hip_bfloat16 h = __float2bfloat16(f);
    return *reinterpret_cast<short*>(&h);
}

__device__ __forceinline__ float bf2f(short s) {
    return __uint_as_float(((unsigned int)(unsigned short)s) << 16);
}

// ---------------------------------------------------------------------------
// 0) W (512 x J fp32, row-major) -> B-fragment-major bf16:
//    dst[((kb32*(J/16)+ntile)*64 + lane)*8 + j] =
//       W[kb32*32 + (lane>>4)*8 + j][ntile*16 + (lane&15)]
// ---------------------------------------------------------------------------
__global__ __launch_bounds__(256) void conv_w(
    const float* __restrict__ W, short* __restrict__ dst, int J)
{
    int idx = blockIdx.x * 256 + threadIdx.x;
    int lane = idx & 63;
    int blk = idx >> 6;
    int ntiles = J >> 4;
    int ntile = blk % ntiles;
    int kb32 = blk / ntiles;
    int krow = kb32 * 32 + (lane >> 4) * 8;
    int col = ntile * 16 + (lane & 15);
    union { short h[8]; uint4 u; } pk;
    #pragma unroll
    for (int j = 0; j < 8; ++j)
        pk.h[j] = bf16s(W[(size_t)(krow + j) * J + col]);
    *reinterpret_cast<uint4*>(dst + (size_t)idx * 8) = pk.u;
}

// ---------------------------------------------------------------------------
// 1) Fused q,k projection from x fp32. Tile 128 pix x (64q | 64k).
//    4 waves: wr = row-half (MT=4), wsel = q/k. A reg-staged to fragment-major
//    LDS (same layout the verified async16 path produced). Epilogue LDS-staged,
//    16B stores.
// ---------------------------------------------------------------------------
__global__ __launch_bounds__(256) void proj_qk(
    const float* __restrict__ x,
    const short* __restrict__ Wqf, const short* __restrict__ Wkf,
    const float* __restrict__ bq, const float* __restrict__ bk,
    short* __restrict__ q, short* __restrict__ k)
{
    __shared__ __align__(16) short Sbuf[128 * 136];   // staging uses first 8KB; epilogue all
    const int tid = threadIdx.x;
    const int lane = tid & 63;
    const int w = tid >> 6;
    const int mBase = blockIdx.x * 128;
    const int wr = w >> 1;
    const int wsel = w & 1;
    const short* Wf = wsel ? Wkf : Wqf;
    const float* bias = wsel ? bk : bq;

    f32x4 acc[4][4];
    #pragma unroll
    for (int i = 0; i < 4; ++i)
        #pragma unroll
        for (int j = 0; j < 4; ++j) {
            f32x4 z = {0.f, 0.f, 0.f, 0.f};
            acc[i][j] = z;
        }

    for (int kb = 0; kb < 16; ++kb) {
        // Stage A-tile (128 pix x 32 k) fp32 -> bf16 fragment-major.
        #pragma unroll
        for (int s = 0; s < 2; ++s) {
            int seg = tid + 256 * s;          // 512 segs of 8 floats
            int r = seg >> 2, kq = seg & 3;
            const float* src = x + (size_t)(mBase + r) * 512 + kb * 32 + kq * 8;
            float4 f0 = *reinterpret_cast<const float4*>(src);
            float4 f1 = *reinterpret_cast<const float4*>(src + 4);
            union { short h[8]; bf16x8 v; } pk;
            pk.h[0] = bf16s(f0.x); pk.h[1] = bf16s(f0.y);
            pk.h[2] = bf16s(f0.z); pk.h[3] = bf16s(f0.w);
            pk.h[4] = bf16s(f1.x); pk.h[5] = bf16s(f1.y);
            pk.h[6] = bf16s(f1.z); pk.h[7] = bf16s(f1.w);
            int dlane = (r & 15) + 16 * kq;
            *reinterpret_cast<bf16x8*>(&Sbuf[(r >> 4) * 512 + dlane * 8]) = pk.v;
        }
        __syncthreads();

        bf16x8 bf[4], af[4];
        #pragma unroll
        for (int jn = 0; jn < 4; ++jn)
            bf[jn] = *reinterpret_cast<const bf16x8*>(
                Wf + ((size_t)(kb * 4 + jn) * 64 + lane) * 8);
        #pragma unroll
        for (int i = 0; i < 4; ++i)
            af[i] = *reinterpret_cast<const bf16x8*>(&Sbuf[(wr * 4 + i) * 512 + lane * 8]);
        #pragma unroll
        for (int i = 0; i < 4; ++i)
            #pragma unroll
            for (int jn = 0; jn < 4; ++jn)
                acc[i][jn] = __builtin_amdgcn_mfma_f32_16x16x32_bf16(
                    af[i], bf[jn], acc[i][jn], 0, 0, 0);
        __syncthreads();
    }

    // Epilogue: stage 128 x (64+64) bf16 tile, then 16B stores.
    const int lrow = (lane >> 4) * 4, cl = lane & 15;
    #pragma unroll
    for (int jn = 0; jn < 4; ++jn) {
        float bc = bias[jn * 16 + cl];
        #pragma unroll
        for (int i = 0; i < 4; ++i) {
            int row = wr * 64 + i * 16 + lrow;
            #pragma unroll
            for (int r = 0; r < 4; ++r)
                Sbuf[(row + r) * 136 + wsel * 64 + jn * 16 + cl] =
                    bf16s(acc[i][jn][r] + bc);
        }
    }
    __syncthreads();
    #pragma unroll
    for (int i = 0; i < 8; ++i) {
        int id = tid + 256 * i;               // 2048 chunks
        int arr = id >> 10;
        int rem = id & 1023;
        int pix = rem >> 3, cc = rem & 7;
        bf16x8 vv = *reinterpret_cast<const bf16x8*>(&Sbuf[pix * 136 + arr * 64 + cc * 8]);
        short* dst = arr ? k : q;
        *reinterpret_cast<bf16x8*>(dst + (size_t)(mBase + pix) * 64 + cc * 8) = vv;
    }
}

// ---------------------------------------------------------------------------
// 2) V projection from x fp32, writes vth[c][n] (n = b*9216+h*96+w, w-contig).
//    bid = mTile*4 + slab (slab-fastest -> A-tile shared via L2/L3).
//    Tile 128 x 128, 4 waves 2x2. Epilogue: short4 column stores.
// ---------------------------------------------------------------------------
__global__ __launch_bounds__(256) void proj_v(
    const float* __restrict__ x, const short* __restrict__ Wvf,
    const float* __restrict__ bv, short* __restrict__ vth)
{
    __shared__ __align__(16) short Albuf[128 * 32];   // 8KB fragment-major
    const int tid = threadIdx.x;
    const int lane = tid & 63;
    const int w = tid >> 6;
    const int bid = blockIdx.x;
    const int mBase = (bid >> 2) * 128;
    const int nBase = (bid & 3) * 128;

    const int wr = w >> 1, wc = w & 1;
    const int nTile0 = (nBase >> 4) + wc * 4;

    f32x4 acc[4][4];
    #pragma unroll
    for (int i = 0; i < 4; ++i)
        #pragma unroll
        for (int j = 0; j < 4; ++j) {
            f32x4 z = {0.f, 0.f, 0.f, 0.f};
            acc[i][j] = z;
        }

    for (int kb = 0; kb < 16; ++kb) {
        #pragma unroll
        for (int s = 0; s < 2; ++s) {
            int seg = tid + 256 * s;
            int r = seg >> 2, kq = seg & 3;
            const float* src = x + (size_t)(mBase + r) * 512 + kb * 32 + kq * 8;
            float4 f0 = *reinterpret_cast<const float4*>(src);
            float4 f1 = *reinterpret_cast<const float4*>(src + 4);
            union { short h[8]; bf16x8 v; } pk;
            pk.h[0] = bf16s(f0.x); pk.h[1] = bf16s(f0.y);
            pk.h[2] = bf16s(f0.z); pk.h[3] = bf16s(f0.w);
            pk.h[4] = bf16s(f1.x); pk.h[5] = bf16s(f1.y);
            pk.h[6] = bf16s(f1.z); pk.h[7] = bf16s(f1.w);
            int dlane = (r & 15) + 16 * kq;
            *reinterpret_cast<bf16x8*>(&Albuf[(r >> 4) * 512 + dlane * 8]) = pk.v;
        }
        __syncthreads();

        bf16x8 bf[4], af[4];
        #pragma unroll
        for (int jn = 0; jn < 4; ++jn)
            bf[jn] = *reinterpret_cast<const bf16x8*>(
                Wvf + ((size_t)(kb * 32 + nTile0 + jn) * 64 + lane) * 8);
        #pragma unroll
        for (int i = 0; i < 4; ++i)
            af[i] = *reinterpret_cast<const bf16x8*>(&Albuf[(wr * 4 + i) * 512 + lane * 8]);
        #pragma unroll
        for (int i = 0; i < 4; ++i)
            #pragma unroll
            for (int jn = 0; jn < 4; ++jn)
                acc[i][jn] = __builtin_amdgcn_mfma_f32_16x16x32_bf16(
                    af[i], bf[jn], acc[i][jn], 0, 0, 0);
        __syncthreads();
    }

    const int lrow = (lane >> 4) * 4, lcol = lane & 15;
    #pragma unroll
    for (int jn = 0; jn < 4; ++jn) {
        int col = nBase + wc * 64 + jn * 16 + lcol;
        float bc = bv[col];
        #pragma unroll
        for (int i = 0; i < 4; ++i) {
            int row = mBase + wr * 64 + i * 16 + lrow;
            short4 st;
            st.x = bf16s(acc[i][jn][0] + bc);
            st.y = bf16s(acc[i][jn][1] + bc);
            st.z = bf16s(acc[i][jn][2] + bc);
            st.w = bf16s(acc[i][jn][3] + bc);
            *reinterpret_cast<short4*>(vth + (size_t)col * NPIX + row) = st;
        }
    }
}

// ---------------------------------------------------------------------------
// 3) vth[c][b][h][w] -> vtv[c][b][w][h]. One (c,b) plane (9216 shorts, 18KB,
//    fully contiguous src AND dst) per block. 4096 blocks.
// ---------------------------------------------------------------------------
__global__ __launch_bounds__(256) void transpose_vtv(
    const short* __restrict__ vth, short* __restrict__ vtv)
{
    __shared__ short T[96 * 97];
    const int tid = threadIdx.x;
    const size_t plane = (size_t)blockIdx.x * 9216;   // planes indexed (c*8+b)
    const short* src = vth + plane;
    short* dst = vtv + plane;

    for (int id = tid; id < 1152; id += 256) {
        int h = id / 12, w8 = (id % 12) * 8;
        bf16x8 v = *reinterpret_cast<const bf16x8*>(src + h * 96 + w8);
        #pragma unroll
        for (int j = 0; j < 8; ++j) T[h * 97 + w8 + j] = v[j];
    }
    __syncthreads();
    for (int id = tid; id < 1152; id += 256) {
        int ww = id / 12, h8 = (id % 12) * 8;
        union { short h[8]; bf16x8 v; } pk;
        #pragma unroll
        for (int j = 0; j < 8; ++j) pk.h[j] = T[(h8 + j) * 97 + ww];
        *reinterpret_cast<bf16x8*>(dst + ww * 96 + h8) = pk.v;
    }
}

// ---------------------------------------------------------------------------
// 4) Scores via MFMA. blockIdx.y==0: vertical, ==1: horizontal.
//    LDS-staged epilogue -> float4 stores.
// ---------------------------------------------------------------------------
__global__ __launch_bounds__(256) void cc_scores(
    const short* __restrict__ Q,   // N x 64 bf16
    const short* __restrict__ K,   // N x 64 bf16
    float* __restrict__ S)         // N x 192 fp32
{
    __shared__ __align__(16) float Ss[96 * 100];
    const int tid = threadIdx.x;
    const int lane = tid & 63;
    const int wv = tid >> 6;
    const int wr = wv >> 1, wc = wv & 1;
    const bool vert = (blockIdx.y == 0);
    const int b = blockIdx.x / 96;
    const int line = blockIdx.x % 96;

    size_t base;
    int rowStride;
    if (vert) { base = (size_t)b * 9216 + line;       rowStride = 96; }
    else      { base = ((size_t)b * 96 + line) * 96;  rowStride = 1;  }

    const int cl = lane & 15;
    const int q8 = (lane >> 4) * 8;

    f32x4 acc[3][3];
    #pragma unroll
    for (int i = 0; i < 3; ++i)
        #pragma unroll
        for (int j = 0; j < 3; ++j) {
            f32x4 z = {0.f, 0.f, 0.f, 0.f};
            acc[i][j] = z;
        }

    #pragma unroll
    for (int kb = 0; kb < 2; ++kb) {
        bf16x8 af[3], bf[3];
        #pragma unroll
        for (int mt = 0; mt < 3; ++mt) {
            size_t n = base + (size_t)(wr * 48 + mt * 16 + cl) * rowStride;
            af[mt] = *reinterpret_cast<const bf16x8*>(Q + n * 64 + kb * 32 + q8);
        }
        #pragma unroll
        for (int nt = 0; nt < 3; ++nt) {
            size_t n = base + (size_t)(wc * 48 + nt * 16 + cl) * rowStride;
            bf[nt] = *reinterpret_cast<const bf16x8*>(K + n * 64 + kb * 32 + q8);
        }
        #pragma unroll
        for (int mt = 0; mt < 3; ++mt)
            #pragma unroll
            for (int nt = 0; nt < 3; ++nt)
                acc[mt][nt] = __builtin_amdgcn_mfma_f32_16x16x32_bf16(
                    af[mt], bf[nt], acc[mt][nt], 0, 0, 0);
    }

    const int lrow = (lane >> 4) * 4;
    #pragma unroll
    for (int mt = 0; mt < 3; ++mt) {
        #pragma unroll
        for (int r = 0; r < 4; ++r) {
            int i = wr * 48 + mt * 16 + lrow + r;
            #pragma unroll
            for (int nt = 0; nt < 3; ++nt) {
                int j = wc * 48 + nt * 16 + cl;
                Ss[i * 100 + j] = (vert && i == j) ? -1e30f : acc[mt][nt][r];
            }
        }
    }
    __syncthreads();

    const int dirOff = vert ? 0 : 96;
    #pragma unroll
    for (int t = 0; t < 9; ++t) {
        int id = tid + 256 * t;               // 96 rows x 24 float4-chunks
        int i = id / 24, j4 = (id % 24) * 4;
        f32x4 v = *reinterpret_cast<const f32x4*>(&Ss[i * 100 + j4]);
        size_t n = base + (size_t)i * rowStride;
        *reinterpret_cast<f32x4*>(S + n * 192 + dirOff + j4) = v;
    }
}

// ---------------------------------------------------------------------------
// 5) Softmax over 192 logits per pixel. One wave per pixel.
//    Writes bf16 probabilities INTO the row: Av = shorts [0,96), Ah = [96,192).
// ---------------------------------------------------------------------------
__global__ __launch_bounds__(256) void cc_softmax(float* __restrict__ S)
{
    const int tid = threadIdx.x;
    const int lane = tid & 63;
    const size_t n = (size_t)blockIdx.x * 4 + (tid >> 6);
    float* row = S + n * 192;
    float s0 = row[lane], s1 = row[lane + 64], s2 = row[lane + 128];
    float m = fmaxf(s0, fmaxf(s1, s2));
    #pragma unroll
    for (int off = 32; off >= 1; off >>= 1) m = fmaxf(m, __shfl_xor(m, off, 64));
    float e0 = expf(s0 - m), e1 = expf(s1 - m), e2 = expf(s2 - m);
    float sum = e0 + e1 + e2;
    #pragma unroll
    for (int off = 32; off >= 1; off >>= 1) sum += __shfl_xor(sum, off, 64);
    float inv = 1.0f / sum;
    short p0 = bf16s(e0 * inv);
    short p1 = bf16s(e1 * inv);
    short p2 = bf16s(e2 * inv);
    short* av = reinterpret_cast<short*>(row);   // 96 shorts (cols 0..95  = Av)
    short* ah = av + 96;                         // 96 shorts (cols 96..191 = Ah)
    av[lane] = p0;
    if (lane < 32) av[64 + lane] = p1;
    else           ah[lane - 32] = p1;
    ah[32 + lane] = p2;
}

// ---------------------------------------------------------------------------
// 6) Vertical aggregation: Yv[b,h,w][c] = sum_g Av[b,h,w][g] * V[b,g,w][c].
//    M=96(h) N=128(c) K=96(g); B-frags 16B from vtv. LDS-staged epilogue.
// ---------------------------------------------------------------------------
__global__ __launch_bounds__(256) void cc_aggr_v(
    const short* __restrict__ A,     // (short*)S: Av at n*PA
    const short* __restrict__ vtv,   // [512][b*9216+w*96+h]
    short* __restrict__ Yv)          // N x 512 bf16 (row-major pixels)
{
    __shared__ __align__(16) short Yb[96 * 136];
    const int tid = threadIdx.x;
    const int lane = tid & 63;
    const int wv = tid >> 6;
    const int bid = blockIdx.x;
    const int pair = bid >> 2;           // b*96 + w
    const int cBase = (bid & 3) * 128;
    const int b = pair / 96;
    const int w = pair - b * 96;
    const size_t pixBase = (size_t)b * 9216 + w;             // + h*96
    const size_t wBase = (size_t)b * 9216 + (size_t)w * 96;  // vtv: + g

    const int wr = wv >> 1, wc = wv & 1;     // wave tile 48(h) x 64(c)
    const int cl = lane & 15, q = lane >> 4;

    f32x4 acc[3][4];
    #pragma unroll
    for (int i = 0; i < 3; ++i)
        #pragma unroll
        for (int j = 0; j < 4; ++j) {
            f32x4 z = {0.f, 0.f, 0.f, 0.f};
            acc[i][j] = z;
        }

    #pragma unroll
    for (int kb = 0; kb < 3; ++kb) {
        bf16x8 af[3];
        #pragma unroll
        for (int mt = 0; mt < 3; ++mt) {
            size_t n = pixBase + (size_t)(wr * 48 + mt * 16 + cl) * 96;
            af[mt] = *reinterpret_cast<const bf16x8*>(A + n * PA + kb * 32 + q * 8);
        }
        #pragma unroll
        for (int nt = 0; nt < 4; ++nt) {
            int col = cBase + wc * 64 + nt * 16 + cl;
            bf16x8 bv = *reinterpret_cast<const bf16x8*>(
                vtv + (size_t)col * NPIX + wBase + kb * 32 + q * 8);
            #pragma unroll
            for (int mt = 0; mt < 3; ++mt)
                acc[mt][nt] = __builtin_amdgcn_mfma_f32_16x16x32_bf16(
                    af[mt], bv, acc[mt][nt], 0, 0, 0);
        }
    }

    const int lrow = q * 4;
    #pragma unroll
    for (int mt = 0; mt < 3; ++mt) {
        #pragma unroll
        for (int r = 0; r < 4; ++r) {
            int hl = wr * 48 + mt * 16 + lrow + r;
            #pragma unroll
            for (int nt = 0; nt < 4; ++nt)
                Yb[hl * 136 + wc * 64 + nt * 16 + cl] = bf16s(acc[mt][nt][r]);
        }
    }
    __syncthreads();
    #pragma unroll
    for (int i = 0; i < 6; ++i) {
        int id = tid + 256 * i;               // 96 rows x 16 chunks (short8)
        int hh = id >> 4, cc = id & 15;
        bf16x8 v = *reinterpret_cast<const bf16x8*>(&Yb[hh * 136 + cc * 8]);
        *reinterpret_cast<bf16x8*>(
            Yv + (pixBase + (size_t)hh * 96) * 512 + cBase + cc * 8) = v;
    }
}

// ---------------------------------------------------------------------------
// 7) Horizontal aggregation + epilogue:
//    out[n][c] = (Yv[n][c] + sum_u Ah[n][u] * V[rowBase+u][c]) * gamma + X[n][c]
//    yh staged fp32 in LDS; X/Yv/out accessed as float4/short4.
// ---------------------------------------------------------------------------
__global__ __launch_bounds__(256) void cc_aggr_h_final(
    const short* __restrict__ A,             // (short*)S: Ah at n*PA + 96
    const short* __restrict__ vth,           // [512][pixel] (w-contig)
    const short* __restrict__ Yv,            // N x 512 bf16
    const float* __restrict__ X,             // N x 512 fp32
    const float* __restrict__ gamma_p,
    float* __restrict__ out)                 // N x 512 fp32
{
    __shared__ __align__(16) float Yh[96 * 132];
    const int tid = threadIdx.x;
    const int lane = tid & 63;
    const int wv = tid >> 6;
    const int bid = blockIdx.x;
    const int pair = bid >> 2;           // b*96 + h
    const int cBase = (bid & 3) * 128;
    const size_t rowBase = (size_t)pair * 96;   // pixel n = rowBase + u

    const int wr = wv >> 1, wc = wv & 1;     // wave tile 48(w) x 64(c)
    const int cl = lane & 15, q = lane >> 4;

    f32x4 acc[3][4];
    #pragma unroll
    for (int i = 0; i < 3; ++i)
        #pragma unroll
        for (int j = 0; j < 4; ++j) {
            f32x4 z = {0.f, 0.f, 0.f, 0.f};
            acc[i][j] = z;
        }

    #pragma unroll
    for (int kb = 0; kb < 3; ++kb) {
        bf16x8 af[3];
        #pragma unroll
        for (int mt = 0; mt < 3; ++mt) {
            size_t n = rowBase + (size_t)(wr * 48 + mt * 16 + cl);
            af[mt] = *reinterpret_cast<const bf16x8*>(A + n * PA + 96 + kb * 32 + q * 8);
        }
        #pragma unroll
        for (int nt = 0; nt < 4; ++nt) {
            int col = cBase + wc * 64 + nt * 16 + cl;
            bf16x8 bv = *reinterpret_cast<const bf16x8*>(
                vth + (size_t)col * NPIX + rowBase + kb * 32 + q * 8);
            #pragma unroll
            for (int mt = 0; mt < 3; ++mt)
                acc[mt][nt] = __builtin_amdgcn_mfma_f32_16x16x32_bf16(
                    af[mt], bv, acc[mt][nt], 0, 0, 0);
        }
    }

    const int lrow = q * 4;
    #pragma unroll
    for (int mt = 0; mt < 3; ++mt) {
        #pragma unroll
        for (int r = 0; r < 4; ++r) {
            int wl = wr * 48 + mt * 16 + lrow + r;
            #pragma unroll
            for (int nt = 0; nt < 4; ++nt)
                Yh[wl * 132 + wc * 64 + nt * 16 + cl] = acc[mt][nt][r];
        }
    }
    __syncthreads();

    const float gm = gamma_p[0];
    #pragma unroll
    for (int i = 0; i < 12; ++i) {
        int id = tid + 256 * i;               // 96 rows x 32 float4-chunks
        int rw = id >> 5, c4 = (id & 31) * 4;
        f32x4 yh = *reinterpret_cast<const f32x4*>(&Yh[rw * 132 + c4]);
        size_t off = (rowBase + rw) * 512 + cBase + c4;
        float4 xx = *reinterpret_cast<const float4*>(X + off);
        short4 yv = *reinterpret_cast<const short4*>(Yv + off);
        float4 o;
        o.x = (yh[0] + bf2f(yv.x)) * gm + xx.x;
        o.y = (yh[1] + bf2f(yv.y)) * gm + xx.y;
        o.z = (yh[2] + bf2f(yv.z)) * gm + xx.z;
        o.w = (yh[3] + bf2f(yv.w)) * gm + xx.w;
        *reinterpret_cast<float4*>(out + off) = o;
    }
}

// ---------------------------------------------------------------------------
extern "C" void kernel_launch(void* const* d_in, const int* in_sizes, int n_in,
                              void* d_out, int out_size, void* d_ws, size_t ws_size,
                              hipStream_t stream) {
    const float* x     = (const float*)d_in[0];
    const float* Wq    = (const float*)d_in[1];
    const float* bq    = (const float*)d_in[2];
    const float* Wk    = (const float*)d_in[3];
    const float* bk    = (const float*)d_in[4];
    const float* Wv    = (const float*)d_in[5];
    const float* bv    = (const float*)d_in[6];
    const float* gamma = (const float*)d_in[7];
    float* out = (float*)d_out;

    // Workspace (shorts unless noted), ~302 MB total:
    //   Wqf/Wkf: 512*64 each; Wvf: 512*512
    //   q,k : NPIX*64 each
    //   vth : NPIX*512  (c-major, w-contig pixels)
    //   vtv : NPIX*512  (c-major, h-contig pixels)
    //   Yv  : NPIX*512  (pixel-major)
    //   S   : NPIX*192 fp32 (also hosts bf16 Av/Ah)
    short* Wqf = (short*)d_ws;
    short* Wkf = Wqf + 512 * 64;
    short* Wvf = Wkf + 512 * 64;
    short* q   = Wvf + 512 * 512;
    short* k   = q + (size_t)NPIX * CQ;
    short* vth = k + (size_t)NPIX * CQ;
    short* vtv = vth + (size_t)NPIX * CC;
    short* Yv  = vtv + (size_t)NPIX * CC;
    float* S   = (float*)(Yv + (size_t)NPIX * CC);

    conv_w<<<16, 256, 0, stream>>>(Wq, Wqf, 64);
    conv_w<<<16, 256, 0, stream>>>(Wk, Wkf, 64);
    conv_w<<<128, 256, 0, stream>>>(Wv, Wvf, 512);

    proj_qk<<<NPIX / 128, 256, 0, stream>>>(x, Wqf, Wkf, bq, bk, q, k);
    proj_v<<<(NPIX / 128) * 4, 256, 0, stream>>>(x, Wvf, bv, vth);
    transpose_vtv<<<4096, 256, 0, stream>>>(vth, vtv);

    cc_scores<<<dim3(8 * 96, 2), 256, 0, stream>>>(q, k, S);
    cc_softmax<<<NPIX / 4, 256, 0, stream>>>(S);

    cc_aggr_v<<<768 * 4, 256, 0, stream>>>((const short*)S, vtv, Yv);
    cc_aggr_h_final<<<768 * 4, 256, 0, stream>>>(
        (const short*)S, vth, Yv, x, gamma, out);
}